// Round 13
// baseline (44.825 us; speedup 1.0000x reference)
//
#include <hip/hip_runtime.h>

#define BB 8
#define TT 24
#define NN 4096   // C*C
#define HH 32
#define JT 64     // j-tile width
#define UPB (TT*HH) // 768
#define CTRS 16   // counter stride (words)
#define NT 512    // threads per block

// ---------------- K1: norm (192 blocks) + z0raw = Edge@W0 (512 blocks) ----------------
__global__ __launch_bounds__(NT) void k_phase1(const float* __restrict__ Flow,
                                               const float* __restrict__ Edge,
                                               const float* __restrict__ W0,
                                               float* __restrict__ rn,
                                               float* __restrict__ s,
                                               float* __restrict__ uz,
                                               float* __restrict__ z0raw) {
    const int blk = blockIdx.x;
    const int tid = threadIdx.x;

    if (blk < BB * TT) {
        const float4* x = (const float4*)(Flow + (size_t)blk * NN);
        float sq = 0.f, sm = 0.f;
#pragma unroll
        for (int i = 0; i < 2; ++i) {
            float4 v = x[tid + i * NT];
            sq += v.x * v.x + v.y * v.y + v.z * v.z + v.w * v.w;
            sm += v.x + v.y + v.z + v.w;
        }
#pragma unroll
        for (int off = 32; off > 0; off >>= 1) {
            sq += __shfl_down(sq, off);
            sm += __shfl_down(sm, off);
        }
        __shared__ float rss[8], rsm[8];
        int wave = tid >> 6, lane = tid & 63;
        if (lane == 0) { rss[wave] = sq; rsm[wave] = sm; }
        __syncthreads();
        if (tid == 0) {
            float tss = 0.f, tsm = 0.f;
#pragma unroll
            for (int w = 0; w < 8; ++w) { tss += rss[w]; tsm += rsm[w]; }
            float r = 1.0f / fmaxf(sqrtf(tss), 1e-12f);
            rn[blk] = r;
            s[blk] = tsm * r;
        }
        // zero u (18432 floats) + ctr (2*BB*CTRS = 256 words)
        int gid = blk * NT + tid;
        if (gid < 3 * BB * TT * HH + 2 * BB * CTRS) uz[gid] = 0.f;
    } else {
        const int g = blk - BB * TT;
        const int b = g >> 6;
        const int j0 = (g & 63) * JT;

        __shared__ float xs[JT][33];
        __shared__ float Ws[32][32];
        for (int i = tid; i < 1024; i += NT) Ws[i >> 5][i & 31] = W0[i];
        {
            float4 v = ((const float4*)(Edge + ((size_t)b * NN + j0) * HH))[tid];
            int r0 = tid >> 3, c0 = (tid & 7) * 4;
            xs[r0][c0] = v.x; xs[r0][c0 + 1] = v.y; xs[r0][c0 + 2] = v.z; xs[r0][c0 + 3] = v.w;
        }
        __syncthreads();
        const int r = tid >> 3;
        const int h0 = (tid & 7) * 4;
        float zr[4];
#pragma unroll
        for (int hh = 0; hh < 4; ++hh) {
            float acc = 0.f;
#pragma unroll
            for (int e = 0; e < 32; ++e) acc += xs[r][e] * Ws[e][h0 + hh];
            zr[hh] = acc;
        }
        float* zb = z0raw + ((size_t)b * NN + j0 + r) * HH + h0;
        ((float4*)zb)[0] = make_float4(zr[0], zr[1], zr[2], zr[3]);
    }
}

// ---------------- K2: dinv + u0 + [u0 barrier] + B(0)+A(1) -> z1raw, u1 ----------------
// Stages Flow/z0 once; di lives in a register across both phases.
__global__ __launch_bounds__(NT, 4) void k_dBA(const float* __restrict__ Flow,
                                               const float* __restrict__ rn,
                                               const float* __restrict__ s,
                                               const float* __restrict__ z0raw,
                                               const float* __restrict__ bias0,
                                               const float* __restrict__ W1,
                                               float* __restrict__ dinv,
                                               float* __restrict__ u0,
                                               float* __restrict__ u1,
                                               unsigned* __restrict__ ctr,
                                               float* __restrict__ z1raw) {
    const int blk = blockIdx.x;
    const int b = blk >> 6;
    const int j0 = (blk & 63) * JT;
    const int tid = threadIdx.x;

    __shared__ float xns[TT][JT];
    __shared__ float zs[JT][33];
    __shared__ float xs[JT][33];
    __shared__ float Ws[32][32];
    __shared__ float us[TT][32];
    __shared__ float sS[TT];
    __shared__ float bs[32];

    if (tid < TT) sS[tid] = s[b * TT + tid];
    if (tid < 32) bs[tid] = bias0[tid];
    for (int i = tid; i < 1024; i += NT) Ws[i >> 5][i & 31] = W1[i];
    {
        float4 v = ((const float4*)(z0raw + ((size_t)b * NN + j0) * HH))[tid];
        int r0 = tid >> 3, c0 = (tid & 7) * 4;
        zs[r0][c0] = v.x; zs[r0][c0 + 1] = v.y; zs[r0][c0 + 2] = v.z; zs[r0][c0 + 3] = v.w;
    }
    if (tid < TT * (JT / 4)) {
        int t = tid >> 4, c0 = (tid & 15) * 4;
        float4 v = ((const float4*)(Flow + (size_t)b * TT * NN + (size_t)t * NN + j0))[tid & 15];
        float rt = rn[b * TT + t];
        xns[t][c0] = v.x * rt; xns[t][c0 + 1] = v.y * rt;
        xns[t][c0 + 2] = v.z * rt; xns[t][c0 + 3] = v.w * rt;
    }
    __syncthreads();

    const int r = tid >> 3;
    const int h0 = (tid & 7) * 4;
    float deg = 1.0f;
#pragma unroll
    for (int t = 0; t < TT; ++t) deg += xns[t][r] * sS[t];
    const float di = (deg > 0.f) ? rsqrtf(deg) : 0.f;
    if ((tid & 7) == 0) dinv[b * NN + j0 + r] = di;   // for k_BAfin
#pragma unroll
    for (int hh = 0; hh < 4; ++hh) zs[r][h0 + hh] *= di;   // zs = y-hat = di*z0raw
    __syncthreads();

    // u0 partials (memory-side atomics)
#pragma unroll
    for (int k = 0; k < 2; ++k) {
        int p = tid + k * NT;
        if (p < UPB) {
            int t = p >> 5, h = p & 31;
            float acc = 0.f;
#pragma unroll 8
            for (int rr = 0; rr < JT; ++rr) acc += xns[t][rr] * zs[rr][h];
            atomicAdd(&u0[b * UPB + t * HH + h], acc);
        }
    }

    // relaxed per-batch barrier on u0 (fan-in 64; all 512 blocks resident at 2/CU)
    __syncthreads();   // compiler drains vmcnt before s_barrier
    if (tid == 0) {
        unsigned* c = ctr + b * CTRS;
        __hip_atomic_fetch_add(c, 1u, __ATOMIC_RELAXED, __HIP_MEMORY_SCOPE_AGENT);
        int lim = 1 << 22;
        while (__hip_atomic_load(c, __ATOMIC_RELAXED, __HIP_MEMORY_SCOPE_AGENT) < 64u && --lim)
            __builtin_amdgcn_s_sleep(1);
    }
    __syncthreads();

    // consume u0 (uncached relaxed atomic loads)
#pragma unroll
    for (int k = 0; k < 2; ++k) {
        int p = tid + k * NT;
        if (p < UPB)
            us[p >> 5][p & 31] = __hip_atomic_load(&u0[b * UPB + p], __ATOMIC_RELAXED,
                                                   __HIP_MEMORY_SCOPE_AGENT);
    }
    __syncthreads();

    // B(0): x1 rows -> xs   (zs already holds y-hat = di*z0raw)
#pragma unroll
    for (int hh = 0; hh < 4; ++hh) {
        int h = h0 + hh;
        float acc = 0.f;
#pragma unroll
        for (int t = 0; t < TT; ++t) acc += xns[t][r] * us[t][h];
        xs[r][h] = fmaxf(di * (acc + zs[r][h]) + bs[h], 0.f);
    }
    // A(1): threads 8r..8r+7 (contiguous within one wave64) wrote xs[r][0..31];
    // same-wave program-order LDS visibility (validated R1..R11)
    float zr[4];
#pragma unroll
    for (int hh = 0; hh < 4; ++hh) {
        float acc = 0.f;
#pragma unroll
        for (int e = 0; e < 32; ++e) acc += xs[r][e] * Ws[e][h0 + hh];
        zr[hh] = acc;                    // raw z1
        zs[r][h0 + hh] = di * zr[hh];    // scaled, for u1 partial
    }
    float* zb = z1raw + ((size_t)b * NN + j0 + r) * HH + h0;
    ((float4*)zb)[0] = make_float4(zr[0], zr[1], zr[2], zr[3]);
    __syncthreads();

    // u1 partials
#pragma unroll
    for (int k = 0; k < 2; ++k) {
        int p = tid + k * NT;
        if (p < UPB) {
            int t = p >> 5, h = p & 31;
            float acc = 0.f;
#pragma unroll 8
            for (int rr = 0; rr < JT; ++rr) acc += xns[t][rr] * zs[rr][h];
            atomicAdd(&u1[b * UPB + t * HH + h], acc);
        }
    }
}

// ---------------- K3: fused B(1)+A(2) + in-kernel u2 barrier + final B -> out ----------------
__global__ __launch_bounds__(NT, 4) void k_BAfin(const float* __restrict__ zraw_in,
                                                 const float* __restrict__ Flow,
                                                 const float* __restrict__ rn,
                                                 const float* __restrict__ u_in,
                                                 const float* __restrict__ dinv,
                                                 const float* __restrict__ bias1,
                                                 const float* __restrict__ W2,
                                                 const float* __restrict__ bias2,
                                                 float* __restrict__ u2,
                                                 unsigned* __restrict__ ctr,
                                                 float* __restrict__ out) {
    const int blk = blockIdx.x;
    const int b = blk >> 6;
    const int j0 = (blk & 63) * JT;
    const int tid = threadIdx.x;

    __shared__ float us[TT][32];
    __shared__ float xns[TT][JT];
    __shared__ float Ws[32][32];
    __shared__ float xs[JT][33];
    __shared__ float zs[JT][33];
    __shared__ float b1s[32], b2s[32];

    if (tid < 32) { b1s[tid] = bias1[tid]; b2s[tid] = bias2[tid]; }
    for (int i = tid; i < 1024; i += NT) Ws[i >> 5][i & 31] = W2[i];
    if (tid < UPB / 4) {
        float4 v = ((const float4*)(u_in + b * UPB))[tid];
        int t = tid >> 3, c0 = (tid & 7) * 4;
        us[t][c0] = v.x; us[t][c0 + 1] = v.y; us[t][c0 + 2] = v.z; us[t][c0 + 3] = v.w;
    }
    {
        float4 v = ((const float4*)(zraw_in + ((size_t)b * NN + j0) * HH))[tid];
        int r0 = tid >> 3, c0 = (tid & 7) * 4;
        zs[r0][c0] = v.x; zs[r0][c0 + 1] = v.y; zs[r0][c0 + 2] = v.z; zs[r0][c0 + 3] = v.w;
    }
    if (tid < TT * (JT / 4)) {
        int t = tid >> 4, c0 = (tid & 15) * 4;
        float4 v = ((const float4*)(Flow + (size_t)b * TT * NN + (size_t)t * NN + j0))[tid & 15];
        float rt = rn[b * TT + t];
        xns[t][c0] = v.x * rt; xns[t][c0 + 1] = v.y * rt;
        xns[t][c0 + 2] = v.z * rt; xns[t][c0 + 3] = v.w * rt;
    }
    const int r = tid >> 3;
    const int h0 = (tid & 7) * 4;
    const float di = dinv[b * NN + j0 + r];
    __syncthreads();

    // B(1): x2 rows
    float zreg[4];
#pragma unroll
    for (int hh = 0; hh < 4; ++hh) zreg[hh] = di * zs[r][h0 + hh];
#pragma unroll
    for (int hh = 0; hh < 4; ++hh) {
        int h = h0 + hh;
        float acc = 0.f;
#pragma unroll
        for (int t = 0; t < TT; ++t) acc += xns[t][r] * us[t][h];
        xs[r][h] = fmaxf(di * (acc + zreg[hh]) + b1s[h], 0.f);
    }
    // A(2): z2 scaled -> zs only (no global write)
#pragma unroll
    for (int hh = 0; hh < 4; ++hh) {
        float acc = 0.f;
#pragma unroll
        for (int e = 0; e < 32; ++e) acc += xs[r][e] * Ws[e][h0 + hh];
        zs[r][h0 + hh] = di * acc;
    }
    __syncthreads();

    // u2 partials (memory-side atomics)
#pragma unroll
    for (int k = 0; k < 2; ++k) {
        int p = tid + k * NT;
        if (p < UPB) {
            int t = p >> 5, h = p & 31;
            float acc = 0.f;
#pragma unroll 8
            for (int rr = 0; rr < JT; ++rr) acc += xns[t][rr] * zs[rr][h];
            atomicAdd(&u2[b * UPB + t * HH + h], acc);
        }
    }

    // relaxed per-batch barrier (fan-in 64; all 512 blocks resident at 2/CU)
    __syncthreads();   // compiler drains vmcnt before s_barrier
    if (tid == 0) {
        unsigned* c = ctr + b * CTRS;
        __hip_atomic_fetch_add(c, 1u, __ATOMIC_RELAXED, __HIP_MEMORY_SCOPE_AGENT);
        int lim = 1 << 22;
        while (__hip_atomic_load(c, __ATOMIC_RELAXED, __HIP_MEMORY_SCOPE_AGENT) < 64u && --lim)
            __builtin_amdgcn_s_sleep(1);
    }
    __syncthreads();

    // consume u2 (uncached relaxed atomic loads)
#pragma unroll
    for (int k = 0; k < 2; ++k) {
        int p = tid + k * NT;
        if (p < UPB)
            us[p >> 5][p & 31] = __hip_atomic_load(&u2[b * UPB + p], __ATOMIC_RELAXED,
                                                   __HIP_MEMORY_SCOPE_AGENT);
    }
    __syncthreads();

    // final B -> out (zs still holds di*z2)
    float o[4];
#pragma unroll
    for (int hh = 0; hh < 4; ++hh) {
        int h = h0 + hh;
        float acc = 0.f;
#pragma unroll
        for (int t = 0; t < TT; ++t) acc += xns[t][r] * us[t][h];
        o[hh] = fmaxf(di * (acc + zs[r][h]) + b2s[h], 0.f);
    }
    float* orow = out + ((size_t)b * NN + j0 + r) * HH + h0;
    ((float4*)orow)[0] = make_float4(o[0], o[1], o[2], o[3]);
}

extern "C" void kernel_launch(void* const* d_in, const int* in_sizes, int n_in,
                              void* d_out, int out_size, void* d_ws, size_t ws_size,
                              hipStream_t stream) {
    const float* Flow = (const float*)d_in[0];
    const float* Edge = (const float*)d_in[1];
    const float* W0 = (const float*)d_in[2];
    const float* b0 = (const float*)d_in[3];
    const float* W1 = (const float*)d_in[4];
    const float* b1 = (const float*)d_in[5];
    const float* W2 = (const float*)d_in[6];
    const float* b2 = (const float*)d_in[7];
    float* out = (float*)d_out;

    float* ws = (float*)d_ws;
    float* rn    = ws;                                  // B*T
    float* s     = rn + BB * TT;                        // B*T
    float* dinv  = s + BB * TT;                         // B*N
    float* zA    = dinv + (size_t)BB * NN;              // B*N*H (raw z0)
    float* zB    = zA + (size_t)BB * NN * HH;           // B*N*H (raw z1)
    float* u     = zB + (size_t)BB * NN * HH;           // 3*B*T*H
    unsigned* ctr = (unsigned*)(u + 3 * BB * UPB);      // 2*B*CTRS words
    float* u0 = u, *u1 = u + BB * UPB, *u2 = u + 2 * BB * UPB;
    unsigned* ctr0 = ctr;
    unsigned* ctr1 = ctr + BB * CTRS;

    k_phase1<<<dim3(BB * TT + 512), NT, 0, stream>>>(Flow, Edge, W0, rn, s, u, zA);
    k_dBA<<<dim3(512), NT, 0, stream>>>(Flow, rn, s, zA, b0, W1, dinv, u0, u1, ctr0, zB);
    k_BAfin<<<dim3(512), NT, 0, stream>>>(zB, Flow, rn, u1, dinv, b1, W2, b2,
                                          u2, ctr1, out);
}

// Round 14
// 41.547 us; speedup vs baseline: 1.0789x; 1.0789x over previous
//
#include <hip/hip_runtime.h>

#define BB 8
#define TT 24
#define NN 4096   // C*C
#define HH 32
#define JT 64     // j-tile width
#define UPB (TT*HH) // 768
#define CTRS 16   // counter stride (words)
#define NT 512    // threads per block

// ---------------- K1: norm (192 blocks) + z0raw = Edge@W0 (512 blocks) ----------------
__global__ __launch_bounds__(NT) void k_phase1(const float* __restrict__ Flow,
                                               const float* __restrict__ Edge,
                                               const float* __restrict__ W0,
                                               float* __restrict__ rn,
                                               float* __restrict__ s,
                                               float* __restrict__ uz,
                                               float* __restrict__ z0raw) {
    const int blk = blockIdx.x;
    const int tid = threadIdx.x;

    if (blk < BB * TT) {
        const float4* x = (const float4*)(Flow + (size_t)blk * NN);
        float sq = 0.f, sm = 0.f;
#pragma unroll
        for (int i = 0; i < 2; ++i) {
            float4 v = x[tid + i * NT];
            sq += v.x * v.x + v.y * v.y + v.z * v.z + v.w * v.w;
            sm += v.x + v.y + v.z + v.w;
        }
#pragma unroll
        for (int off = 32; off > 0; off >>= 1) {
            sq += __shfl_down(sq, off);
            sm += __shfl_down(sm, off);
        }
        __shared__ float rss[8], rsm[8];
        int wave = tid >> 6, lane = tid & 63;
        if (lane == 0) { rss[wave] = sq; rsm[wave] = sm; }
        __syncthreads();
        if (tid == 0) {
            float tss = 0.f, tsm = 0.f;
#pragma unroll
            for (int w = 0; w < 8; ++w) { tss += rss[w]; tsm += rsm[w]; }
            float r = 1.0f / fmaxf(sqrtf(tss), 1e-12f);
            rn[blk] = r;
            s[blk] = tsm * r;
        }
        // zero u (18432 floats) + ctr (128 words)
        int gid = blk * NT + tid;
        if (gid < 3 * BB * TT * HH + BB * CTRS) uz[gid] = 0.f;
    } else {
        const int g = blk - BB * TT;
        const int b = g >> 6;
        const int j0 = (g & 63) * JT;

        __shared__ float xs[JT][33];
        __shared__ float Ws[32][32];
        for (int i = tid; i < 1024; i += NT) Ws[i >> 5][i & 31] = W0[i];
        {
            float4 v = ((const float4*)(Edge + ((size_t)b * NN + j0) * HH))[tid];
            int r0 = tid >> 3, c0 = (tid & 7) * 4;
            xs[r0][c0] = v.x; xs[r0][c0 + 1] = v.y; xs[r0][c0 + 2] = v.z; xs[r0][c0 + 3] = v.w;
        }
        __syncthreads();
        const int r = tid >> 3;
        const int h0 = (tid & 7) * 4;
        float zr[4];
#pragma unroll
        for (int hh = 0; hh < 4; ++hh) {
            float acc = 0.f;
#pragma unroll
            for (int e = 0; e < 32; ++e) acc += xs[r][e] * Ws[e][h0 + hh];
            zr[hh] = acc;
        }
        float* zb = z0raw + ((size_t)b * NN + j0 + r) * HH + h0;
        ((float4*)zb)[0] = make_float4(zr[0], zr[1], zr[2], zr[3]);
    }
}

// ---------------- K2: dinv + u0 partials ----------------
__global__ __launch_bounds__(NT) void k_dinvU0(const float* __restrict__ Flow,
                                               const float* __restrict__ rn,
                                               const float* __restrict__ s,
                                               const float* __restrict__ z0raw,
                                               float* __restrict__ dinv,
                                               float* __restrict__ u0) {
    const int blk = blockIdx.x;
    const int b = blk >> 6;
    const int j0 = (blk & 63) * JT;
    const int tid = threadIdx.x;

    __shared__ float xns[TT][JT];
    __shared__ float zs[JT][33];
    __shared__ float sS[TT];

    if (tid < TT) sS[tid] = s[b * TT + tid];
    {
        float4 v = ((const float4*)(z0raw + ((size_t)b * NN + j0) * HH))[tid];
        int r0 = tid >> 3, c0 = (tid & 7) * 4;
        zs[r0][c0] = v.x; zs[r0][c0 + 1] = v.y; zs[r0][c0 + 2] = v.z; zs[r0][c0 + 3] = v.w;
    }
    if (tid < TT * (JT / 4)) {
        int t = tid >> 4, c0 = (tid & 15) * 4;
        float4 v = ((const float4*)(Flow + (size_t)b * TT * NN + (size_t)t * NN + j0))[tid & 15];
        float rt = rn[b * TT + t];
        xns[t][c0] = v.x * rt; xns[t][c0 + 1] = v.y * rt;
        xns[t][c0 + 2] = v.z * rt; xns[t][c0 + 3] = v.w * rt;
    }
    __syncthreads();

    const int r = tid >> 3;
    const int h0 = (tid & 7) * 4;
    float deg = 1.0f;
#pragma unroll
    for (int t = 0; t < TT; ++t) deg += xns[t][r] * sS[t];
    const float di = (deg > 0.f) ? rsqrtf(deg) : 0.f;
    if ((tid & 7) == 0) dinv[b * NN + j0 + r] = di;
#pragma unroll
    for (int hh = 0; hh < 4; ++hh) zs[r][h0 + hh] *= di;
    __syncthreads();

#pragma unroll
    for (int k = 0; k < 2; ++k) {
        int p = tid + k * NT;
        if (p < UPB) {
            int t = p >> 5, h = p & 31;
            float acc = 0.f;
#pragma unroll 8
            for (int rr = 0; rr < JT; ++rr) acc += xns[t][rr] * zs[rr][h];
            atomicAdd(&u0[b * UPB + t * HH + h], acc);
        }
    }
}

// ---------------- K3: fused B(0)+A(1), raw-z in/out ----------------
__global__ __launch_bounds__(NT) void k_BA(const float* __restrict__ zraw_in,
                                           const float* __restrict__ Flow,
                                           const float* __restrict__ rn,
                                           const float* __restrict__ u_in,
                                           const float* __restrict__ dinv,
                                           const float* __restrict__ bias,
                                           const float* __restrict__ W,
                                           float* __restrict__ zraw_out,
                                           float* __restrict__ u_out) {
    const int blk = blockIdx.x;
    const int b = blk >> 6;
    const int j0 = (blk & 63) * JT;
    const int tid = threadIdx.x;

    __shared__ float us[TT][32];
    __shared__ float xns[TT][JT];
    __shared__ float Ws[32][32];
    __shared__ float xs[JT][33];
    __shared__ float zs[JT][33];
    __shared__ float bs[32];

    if (tid < 32) bs[tid] = bias[tid];
    for (int i = tid; i < 1024; i += NT) Ws[i >> 5][i & 31] = W[i];
    if (tid < UPB / 4) {
        float4 v = ((const float4*)(u_in + b * UPB))[tid];
        int t = tid >> 3, c0 = (tid & 7) * 4;
        us[t][c0] = v.x; us[t][c0 + 1] = v.y; us[t][c0 + 2] = v.z; us[t][c0 + 3] = v.w;
    }
    {
        float4 v = ((const float4*)(zraw_in + ((size_t)b * NN + j0) * HH))[tid];
        int r0 = tid >> 3, c0 = (tid & 7) * 4;
        zs[r0][c0] = v.x; zs[r0][c0 + 1] = v.y; zs[r0][c0 + 2] = v.z; zs[r0][c0 + 3] = v.w;
    }
    if (tid < TT * (JT / 4)) {
        int t = tid >> 4, c0 = (tid & 15) * 4;
        float4 v = ((const float4*)(Flow + (size_t)b * TT * NN + (size_t)t * NN + j0))[tid & 15];
        float rt = rn[b * TT + t];
        xns[t][c0] = v.x * rt; xns[t][c0 + 1] = v.y * rt;
        xns[t][c0 + 2] = v.z * rt; xns[t][c0 + 3] = v.w * rt;
    }
    const int r = tid >> 3;
    const int h0 = (tid & 7) * 4;
    const float di = dinv[b * NN + j0 + r];
    __syncthreads();

    float zreg[4];
#pragma unroll
    for (int hh = 0; hh < 4; ++hh) zreg[hh] = di * zs[r][h0 + hh];
#pragma unroll
    for (int hh = 0; hh < 4; ++hh) {
        int h = h0 + hh;
        float acc = 0.f;
#pragma unroll
        for (int t = 0; t < TT; ++t) acc += xns[t][r] * us[t][h];
        xs[r][h] = fmaxf(di * (acc + zreg[hh]) + bs[h], 0.f);
    }
    // A-phase: threads 8r..8r+7 (contiguous within one wave64) wrote xs[r][0..31];
    // same-wave program-order LDS visibility (validated R1..R12)
    float zr[4];
#pragma unroll
    for (int hh = 0; hh < 4; ++hh) {
        float acc = 0.f;
#pragma unroll
        for (int e = 0; e < 32; ++e) acc += xs[r][e] * Ws[e][h0 + hh];
        zr[hh] = acc;                    // raw
        zs[r][h0 + hh] = di * zr[hh];    // scaled, for u partial
    }
    float* zb = zraw_out + ((size_t)b * NN + j0 + r) * HH + h0;
    ((float4*)zb)[0] = make_float4(zr[0], zr[1], zr[2], zr[3]);
    __syncthreads();

#pragma unroll
    for (int k = 0; k < 2; ++k) {
        int p = tid + k * NT;
        if (p < UPB) {
            int t = p >> 5, h = p & 31;
            float acc = 0.f;
#pragma unroll 8
            for (int rr = 0; rr < JT; ++rr) acc += xns[t][rr] * zs[rr][h];
            atomicAdd(&u_out[b * UPB + t * HH + h], acc);
        }
    }
}

// ---------------- K4: fused B(1)+A(2) + in-kernel u2 barrier + final B -> out ----------------
__global__ __launch_bounds__(NT, 4) void k_BAfin(const float* __restrict__ zraw_in,
                                                 const float* __restrict__ Flow,
                                                 const float* __restrict__ rn,
                                                 const float* __restrict__ u_in,
                                                 const float* __restrict__ dinv,
                                                 const float* __restrict__ bias1,
                                                 const float* __restrict__ W2,
                                                 const float* __restrict__ bias2,
                                                 float* __restrict__ u2,
                                                 unsigned* __restrict__ ctr,
                                                 float* __restrict__ out) {
    const int blk = blockIdx.x;
    const int b = blk >> 6;
    const int j0 = (blk & 63) * JT;
    const int tid = threadIdx.x;

    __shared__ float us[TT][32];
    __shared__ float xns[TT][JT];
    __shared__ float Ws[32][32];
    __shared__ float xs[JT][33];
    __shared__ float zs[JT][33];
    __shared__ float b1s[32], b2s[32];

    if (tid < 32) { b1s[tid] = bias1[tid]; b2s[tid] = bias2[tid]; }
    for (int i = tid; i < 1024; i += NT) Ws[i >> 5][i & 31] = W2[i];
    if (tid < UPB / 4) {
        float4 v = ((const float4*)(u_in + b * UPB))[tid];
        int t = tid >> 3, c0 = (tid & 7) * 4;
        us[t][c0] = v.x; us[t][c0 + 1] = v.y; us[t][c0 + 2] = v.z; us[t][c0 + 3] = v.w;
    }
    {
        float4 v = ((const float4*)(zraw_in + ((size_t)b * NN + j0) * HH))[tid];
        int r0 = tid >> 3, c0 = (tid & 7) * 4;
        zs[r0][c0] = v.x; zs[r0][c0 + 1] = v.y; zs[r0][c0 + 2] = v.z; zs[r0][c0 + 3] = v.w;
    }
    if (tid < TT * (JT / 4)) {
        int t = tid >> 4, c0 = (tid & 15) * 4;
        float4 v = ((const float4*)(Flow + (size_t)b * TT * NN + (size_t)t * NN + j0))[tid & 15];
        float rt = rn[b * TT + t];
        xns[t][c0] = v.x * rt; xns[t][c0 + 1] = v.y * rt;
        xns[t][c0 + 2] = v.z * rt; xns[t][c0 + 3] = v.w * rt;
    }
    const int r = tid >> 3;
    const int h0 = (tid & 7) * 4;
    const float di = dinv[b * NN + j0 + r];
    __syncthreads();

    // B(1): x2 rows
    float zreg[4];
#pragma unroll
    for (int hh = 0; hh < 4; ++hh) zreg[hh] = di * zs[r][h0 + hh];
#pragma unroll
    for (int hh = 0; hh < 4; ++hh) {
        int h = h0 + hh;
        float acc = 0.f;
#pragma unroll
        for (int t = 0; t < TT; ++t) acc += xns[t][r] * us[t][h];
        xs[r][h] = fmaxf(di * (acc + zreg[hh]) + b1s[h], 0.f);
    }
    // A(2): z2 scaled -> zs only (no global write)
#pragma unroll
    for (int hh = 0; hh < 4; ++hh) {
        float acc = 0.f;
#pragma unroll
        for (int e = 0; e < 32; ++e) acc += xs[r][e] * Ws[e][h0 + hh];
        zs[r][h0 + hh] = di * acc;
    }
    __syncthreads();

    // u2 partials (memory-side atomics)
#pragma unroll
    for (int k = 0; k < 2; ++k) {
        int p = tid + k * NT;
        if (p < UPB) {
            int t = p >> 5, h = p & 31;
            float acc = 0.f;
#pragma unroll 8
            for (int rr = 0; rr < JT; ++rr) acc += xns[t][rr] * zs[rr][h];
            atomicAdd(&u2[b * UPB + t * HH + h], acc);
        }
    }

    // relaxed per-batch barrier (fan-in 64; all 512 blocks resident at 2/CU)
    __syncthreads();   // compiler drains vmcnt before s_barrier
    if (tid == 0) {
        unsigned* c = ctr + b * CTRS;
        __hip_atomic_fetch_add(c, 1u, __ATOMIC_RELAXED, __HIP_MEMORY_SCOPE_AGENT);
        int lim = 1 << 22;
        while (__hip_atomic_load(c, __ATOMIC_RELAXED, __HIP_MEMORY_SCOPE_AGENT) < 64u && --lim)
            __builtin_amdgcn_s_sleep(1);
    }
    __syncthreads();

    // consume u2 (uncached relaxed atomic loads)
#pragma unroll
    for (int k = 0; k < 2; ++k) {
        int p = tid + k * NT;
        if (p < UPB)
            us[p >> 5][p & 31] = __hip_atomic_load(&u2[b * UPB + p], __ATOMIC_RELAXED,
                                                   __HIP_MEMORY_SCOPE_AGENT);
    }
    __syncthreads();

    // final B -> out (zs still holds di*z2)
    float o[4];
#pragma unroll
    for (int hh = 0; hh < 4; ++hh) {
        int h = h0 + hh;
        float acc = 0.f;
#pragma unroll
        for (int t = 0; t < TT; ++t) acc += xns[t][r] * us[t][h];
        o[hh] = fmaxf(di * (acc + zs[r][h]) + b2s[h], 0.f);
    }
    float* orow = out + ((size_t)b * NN + j0 + r) * HH + h0;
    ((float4*)orow)[0] = make_float4(o[0], o[1], o[2], o[3]);
}

extern "C" void kernel_launch(void* const* d_in, const int* in_sizes, int n_in,
                              void* d_out, int out_size, void* d_ws, size_t ws_size,
                              hipStream_t stream) {
    const float* Flow = (const float*)d_in[0];
    const float* Edge = (const float*)d_in[1];
    const float* W0 = (const float*)d_in[2];
    const float* b0 = (const float*)d_in[3];
    const float* W1 = (const float*)d_in[4];
    const float* b1 = (const float*)d_in[5];
    const float* W2 = (const float*)d_in[6];
    const float* b2 = (const float*)d_in[7];
    float* out = (float*)d_out;

    float* ws = (float*)d_ws;
    float* rn    = ws;                                  // B*T
    float* s     = rn + BB * TT;                        // B*T
    float* dinv  = s + BB * TT;                         // B*N
    float* zA    = dinv + (size_t)BB * NN;              // B*N*H (raw)
    float* zB    = zA + (size_t)BB * NN * HH;           // B*N*H (raw)
    float* u     = zB + (size_t)BB * NN * HH;           // 3*B*T*H
    unsigned* ctr = (unsigned*)(u + 3 * BB * UPB);      // B*CTRS words
    float* u0 = u, *u1 = u + BB * UPB, *u2 = u + 2 * BB * UPB;

    k_phase1<<<dim3(BB * TT + 512), NT, 0, stream>>>(Flow, Edge, W0, rn, s, u, zA);
    k_dinvU0<<<dim3(512), NT, 0, stream>>>(Flow, rn, s, zA, dinv, u0);
    k_BA<<<dim3(512), NT, 0, stream>>>(zA, Flow, rn, u0, dinv, b0, W1, zB, u1);
    k_BAfin<<<dim3(512), NT, 0, stream>>>(zB, Flow, rn, u1, dinv, b1, W2, b2,
                                          u2, ctr, out);
}